// Round 24
// baseline (40.016 us; speedup 1.0000x reference)
//
#include <hip/hip_runtime.h>

#define NN 4096
#define FIN 256
#define FOUT 64
#define NH 4
#define CAP 128    // max edges/row; Binomial(4096,0.01) P(>127) ~ 1e-30
#define WROW 258   // padded shorts per ws row (516 B -> bank-spread writes)

typedef __attribute__((ext_vector_type(8))) short bf16x8;
typedef __attribute__((ext_vector_type(4))) float f32x4;

__device__ __forceinline__ unsigned short f2bf(float f) {   // RNE f32->bf16
    unsigned u = __float_as_uint(f);
    u = (u + 0x7fff + ((u >> 16) & 1)) >> 16;
    return (unsigned short)u;
}
__device__ __forceinline__ float bf2f(unsigned short s) {
    return __uint_as_float((unsigned)s << 16);
}
__device__ __forceinline__ int mbcnt64(unsigned long long m) {
    return __builtin_amdgcn_mbcnt_hi((unsigned)(m >> 32),
           __builtin_amdgcn_mbcnt_lo((unsigned)m, 0));
}
// raw workgroup barrier: LDS-ordering only -- does NOT drain vmcnt, so
// prefetched global loads stay in flight across it (HK pattern).
__device__ __forceinline__ void wg_barrier() {
    asm volatile("s_waitcnt lgkmcnt(0)" ::: "memory");
    __builtin_amdgcn_s_barrier();
}

// ---------------------------------------------------------------------------
// K1: MFMA hprime (r18 verbatim). Outputs bf16 hb + node-major sd.
// ---------------------------------------------------------------------------
__global__ __launch_bounds__(256) void gat_hprime(
    const float* __restrict__ h, const float* __restrict__ w,
    const float* __restrict__ a_src, const float* __restrict__ a_dst,
    unsigned short* __restrict__ hb, float* __restrict__ sd)
{
    const int b = blockIdx.x, t = threadIdx.x;
    const int head = b & 3, n0 = (b >> 2) * 32;
    const int wv = t >> 6, lane = t & 63;
    const int lrow = lane & 15, lk8 = lane >> 4;

    __shared__ __align__(16) unsigned short ws[64 * WROW];  // 33 KB
    __shared__ float sdbuf[2][2][16][2];

#pragma unroll
    for (int i = 0; i < 16; ++i) {
        const int k  = (t >> 4) + i * 16;
        const int o4 = (t & 15) * 4;
        const float4 v = *(const float4*)(w + ((size_t)head * FIN + k) * FOUT + o4);
        ws[(o4 + 0) * WROW + k] = f2bf(v.x);
        ws[(o4 + 1) * WROW + k] = f2bf(v.y);
        ws[(o4 + 2) * WROW + k] = f2bf(v.z);
        ws[(o4 + 3) * WROW + k] = f2bf(v.w);
    }

    const float* hrow = h + (size_t)(n0 + (wv >> 1) * 16 + lrow) * FIN + lk8 * 8;
    bf16x8 a[8];
#pragma unroll
    for (int ks = 0; ks < 8; ++ks) {
        const float4 v0 = *(const float4*)(hrow + ks * 32);
        const float4 v1 = *(const float4*)(hrow + ks * 32 + 4);
        union { bf16x8 v; unsigned short s[8]; } u;
        u.s[0] = f2bf(v0.x); u.s[1] = f2bf(v0.y);
        u.s[2] = f2bf(v0.z); u.s[3] = f2bf(v0.w);
        u.s[4] = f2bf(v1.x); u.s[5] = f2bf(v1.y);
        u.s[6] = f2bf(v1.z); u.s[7] = f2bf(v1.w);
        a[ks] = u.v;
    }
    __syncthreads();

    const int obase = (wv & 1) * 32;
    f32x4 acc[2] = {{0.f,0.f,0.f,0.f},{0.f,0.f,0.f,0.f}};
#pragma unroll
    for (int ks = 0; ks < 8; ++ks) {
#pragma unroll
        for (int nt = 0; nt < 2; ++nt) {
            const bf16x8 bf = *(const bf16x8*)
                &ws[(obase + nt * 16 + lrow) * WROW + ks * 32 + lk8 * 8];
            acc[nt] = __builtin_amdgcn_mfma_f32_16x16x32_bf16(a[ks], bf, acc[nt], 0, 0, 0);
        }
    }

    const int mbase = n0 + (wv >> 1) * 16 + lk8 * 4;
#pragma unroll
    for (int nt = 0; nt < 2; ++nt)
#pragma unroll
        for (int r = 0; r < 4; ++r)
            hb[((size_t)head * NN + mbase + r) * FOUT + obase + nt * 16 + lrow] =
                f2bf(acc[nt][r]);

    float as_nt[2], ad_nt[2];
#pragma unroll
    for (int nt = 0; nt < 2; ++nt) {
        as_nt[nt] = a_src[head * FOUT + obase + nt * 16 + lrow];
        ad_nt[nt] = a_dst[head * FOUT + obase + nt * 16 + lrow];
    }
    float psr[4] = {0.f,0.f,0.f,0.f}, pdr[4] = {0.f,0.f,0.f,0.f};
#pragma unroll
    for (int nt = 0; nt < 2; ++nt)
#pragma unroll
        for (int r = 0; r < 4; ++r) {
            psr[r] = fmaf(acc[nt][r], as_nt[nt], psr[r]);
            pdr[r] = fmaf(acc[nt][r], ad_nt[nt], pdr[r]);
        }
#pragma unroll
    for (int r = 0; r < 4; ++r)
#pragma unroll
        for (int off = 1; off <= 8; off <<= 1) {
            psr[r] += __shfl_xor(psr[r], off, 64);
            pdr[r] += __shfl_xor(pdr[r], off, 64);
        }
    if (lrow == 0)
#pragma unroll
        for (int r = 0; r < 4; ++r) {
            sdbuf[wv >> 1][wv & 1][lk8 * 4 + r][0] = psr[r];
            sdbuf[wv >> 1][wv & 1][lk8 * 4 + r][1] = pdr[r];
        }
    __syncthreads();
    if ((wv & 1) == 0 && lrow == 0) {
        const int p = wv >> 1;
#pragma unroll
        for (int r = 0; r < 4; ++r) {
            const int n = lk8 * 4 + r;
            const int node = n0 + p * 16 + n;
            sd[(size_t)node * 8 + head]     = sdbuf[p][0][n][0] + sdbuf[p][1][n][0];
            sd[(size_t)node * 8 + 4 + head] = sdbuf[p][0][n][1] + sdbuf[p][1][n][1];
        }
    }
}

// ---------------------------------------------------------------------------
// K2: row-pipelined fused scan+attn. 1024 blocks x 4 rows, 2-deep ping-pong:
// row k+1's 16 KB of adj loads are issued BEFORE row k's tail, and stay in
// flight across the tail because all barriers are raw s_barrier + lgkmcnt
// (no vmcnt drain). Tail = r21's proven pipeline (ballot compact -> scores
// -> per-head softmax -> gather v2 with dwordx2 per edge).
// ---------------------------------------------------------------------------
#define LOADROW(BUF, RR) do {                                              \
    const int4* arow_ = (const int4*)(adj + (size_t)(RR) * NN);            \
    _Pragma("unroll")                                                      \
    for (int it_ = 0; it_ < 4; ++it_)                                      \
        BUF[it_] = arow_[wv * 256 + it_ * 64 + lane];                      \
} while (0)

#define TAIL(BUF, RR) do {                                                 \
    int myoff_[4];                                                         \
    _Pragma("unroll")                                                      \
    for (int it_ = 0; it_ < 4; ++it_) {                                    \
        const unsigned long long b0_ = __ballot(BUF[it_].x != 0);          \
        const unsigned long long b1_ = __ballot(BUF[it_].y != 0);          \
        const unsigned long long b2_ = __ballot(BUF[it_].z != 0);          \
        const unsigned long long b3_ = __ballot(BUF[it_].w != 0);          \
        myoff_[it_] = mbcnt64(b0_) + mbcnt64(b1_) + mbcnt64(b2_) + mbcnt64(b3_); \
        if (lane == 0)                                                     \
            ccnt[wv * 4 + it_] = __popcll(b0_) + __popcll(b1_) +           \
                                 __popcll(b2_) + __popcll(b3_);            \
    }                                                                      \
    wg_barrier();                                                          \
    int cb_[4];                                                            \
    int s_ = 0;                                                            \
    _Pragma("unroll")                                                      \
    for (int k_ = 0; k_ < 16; ++k_) {                                      \
        if ((k_ >> 2) == wv) cb_[k_ & 3] = s_;                             \
        s_ += ccnt[k_];                                                    \
    }                                                                      \
    const int count_ = min(s_, CAP);                                       \
    _Pragma("unroll")                                                      \
    for (int it_ = 0; it_ < 4; ++it_) {                                    \
        int p_ = cb_[it_] + myoff_[it_];                                   \
        const int col0_ = (wv * 256 + it_ * 64 + lane) * 4;                \
        if (BUF[it_].x) { if (p_ < CAP) idx_l[p_] = col0_;     ++p_; }     \
        if (BUF[it_].y) { if (p_ < CAP) idx_l[p_] = col0_ + 1; ++p_; }     \
        if (BUF[it_].z) { if (p_ < CAP) idx_l[p_] = col0_ + 2; ++p_; }     \
        if (BUF[it_].w) { if (p_ < CAP) idx_l[p_] = col0_ + 3; ++p_; }     \
    }                                                                      \
    wg_barrier();                                                          \
    if (t < count_) {                                                      \
        const int j_ = idx_l[t];                                           \
        const float4 sv_ = *(const float4*)(sd + (size_t)(RR) * 8);        \
        const float4 dv_ = *(const float4*)(sd + (size_t)j_ * 8 + 4);      \
        const float s0_ = sv_.x + dv_.x, s1_ = sv_.y + dv_.y;              \
        const float s2_ = sv_.z + dv_.z, s3_ = sv_.w + dv_.w;              \
        sc[0][t] = (s0_ >= 0.f) ? s0_ : 0.2f * s0_;                        \
        sc[1][t] = (s1_ >= 0.f) ? s1_ : 0.2f * s1_;                        \
        sc[2][t] = (s2_ >= 0.f) ? s2_ : 0.2f * s2_;                        \
        sc[3][t] = (s3_ >= 0.f) ? s3_ : 0.2f * s3_;                        \
    }                                                                      \
    wg_barrier();                                                          \
    {                                                                      \
        float m_ = -3.4e38f;                                               \
        for (int p_ = lane; p_ < count_; p_ += 64)                         \
            m_ = fmaxf(m_, sc[wv][p_]);                                    \
        _Pragma("unroll")                                                  \
        for (int off_ = 32; off_ >= 1; off_ >>= 1)                         \
            m_ = fmaxf(m_, __shfl_xor(m_, off_, 64));                      \
        float e_ = 0.f;                                                    \
        for (int p_ = lane; p_ < count_; p_ += 64) {                       \
            const float v_ = __expf(sc[wv][p_] - m_);                      \
            sc[wv][p_] = v_;                                               \
            e_ += v_;                                                      \
        }                                                                  \
        _Pragma("unroll")                                                  \
        for (int off_ = 32; off_ >= 1; off_ >>= 1)                         \
            e_ += __shfl_xor(e_, off_, 64);                                \
        if (lane == 0) inv_sum[wv] = 1.f / e_;                             \
    }                                                                      \
    wg_barrier();                                                          \
    {                                                                      \
        const int hh_ = lane >> 4, og_ = lane & 15;                        \
        const unsigned short* hpb_ = hb + (size_t)hh_ * NN * FOUT + og_ * 4; \
        float4 accv_ = make_float4(0.f, 0.f, 0.f, 0.f);                    \
        for (int p0_ = wv; p0_ < count_; p0_ += 16) {                      \
            int jj_[4]; float ee_[4]; ushort4 hv_[4];                      \
            _Pragma("unroll")                                              \
            for (int k_ = 0; k_ < 4; ++k_) {                               \
                const int pp_ = p0_ + k_ * 4;                              \
                const bool act_ = pp_ < count_;                            \
                jj_[k_] = act_ ? idx_l[pp_] : 0;                           \
                ee_[k_] = act_ ? sc[hh_][pp_] : 0.f;                       \
            }                                                              \
            _Pragma("unroll")                                              \
            for (int k_ = 0; k_ < 4; ++k_)                                 \
                hv_[k_] = *(const ushort4*)(hpb_ + (size_t)jj_[k_] * FOUT); \
            _Pragma("unroll")                                              \
            for (int k_ = 0; k_ < 4; ++k_) {                               \
                accv_.x = fmaf(ee_[k_], bf2f(hv_[k_].x), accv_.x);         \
                accv_.y = fmaf(ee_[k_], bf2f(hv_[k_].y), accv_.y);         \
                accv_.z = fmaf(ee_[k_], bf2f(hv_[k_].z), accv_.z);         \
                accv_.w = fmaf(ee_[k_], bf2f(hv_[k_].w), accv_.w);         \
            }                                                              \
        }                                                                  \
        *(float4*)&accbuf[wv][lane][0] = accv_;                            \
    }                                                                      \
    wg_barrier();                                                          \
    if (wv == 0) {                                                         \
        const int hh_ = lane >> 4, og_ = lane & 15;                        \
        float4 r0_ = *(const float4*)&accbuf[0][lane][0];                  \
        const float4 r1_ = *(const float4*)&accbuf[1][lane][0];            \
        const float4 r2_ = *(const float4*)&accbuf[2][lane][0];            \
        const float4 r3_ = *(const float4*)&accbuf[3][lane][0];            \
        r0_.x += r1_.x + r2_.x + r3_.x;                                    \
        r0_.y += r1_.y + r2_.y + r3_.y;                                    \
        r0_.z += r1_.z + r2_.z + r3_.z;                                    \
        r0_.w += r1_.w + r2_.w + r3_.w;                                    \
        const float is_ = inv_sum[hh_];                                    \
        const float4 bv_ = *(const float4*)(bias + og_ * 4);               \
        float4 o_;                                                         \
        o_.x = r0_.x * is_ + bv_.x;                                        \
        o_.y = r0_.y * is_ + bv_.y;                                        \
        o_.z = r0_.z * is_ + bv_.z;                                        \
        o_.w = r0_.w * is_ + bv_.w;                                        \
        *(float4*)(out + (size_t)(RR) * (NH * FOUT) + hh_ * FOUT + og_ * 4) = o_; \
    }                                                                      \
    wg_barrier();                                                          \
} while (0)

__global__ __launch_bounds__(256) void gat_attn(
    const int* __restrict__ adj, const unsigned short* __restrict__ hb,
    const float* __restrict__ sd, const float* __restrict__ bias,
    float* __restrict__ out)
{
    const int t = threadIdx.x, wv = t >> 6, lane = t & 63;
    const int r0 = blockIdx.x * 4;

    __shared__ int   idx_l[CAP];
    __shared__ float sc[NH][CAP];
    __shared__ int   ccnt[16];
    __shared__ float inv_sum[NH];
    __shared__ float accbuf[4][64][4];

    int4 A[4], B[4];
    LOADROW(A, r0);
    LOADROW(B, r0 + 1);   // in flight across TAIL(A)
    TAIL(A, r0);
    LOADROW(A, r0 + 2);   // in flight across TAIL(B)
    TAIL(B, r0 + 1);
    LOADROW(B, r0 + 3);
    TAIL(A, r0 + 2);
    TAIL(B, r0 + 3);
}

extern "C" void kernel_launch(void* const* d_in, const int* in_sizes, int n_in,
                              void* d_out, int out_size, void* d_ws, size_t ws_size,
                              hipStream_t stream) {
    const float* h     = (const float*)d_in[0];
    const int*   adj   = (const int*)d_in[1];
    const float* w     = (const float*)d_in[2];
    const float* a_src = (const float*)d_in[3];
    const float* a_dst = (const float*)d_in[4];
    const float* bias  = (const float*)d_in[5];
    float* out = (float*)d_out;

    unsigned short* hb = (unsigned short*)d_ws;                 // 2 MB bf16 h'
    float* sd          = (float*)(hb + (size_t)NH * NN * FOUT); // NN*8 floats

    gat_hprime<<<512, 256, 0, stream>>>(h, w, a_src, a_dst, hb, sd);
    gat_attn<<<NN / 4, 256, 0, stream>>>(adj, hb, sd, bias, out);
}

// Round 25
// 35.281 us; speedup vs baseline: 1.1342x; 1.1342x over previous
//
#include <hip/hip_runtime.h>

#define NN 4096
#define FIN 256
#define FOUT 64
#define NH 4
#define CAP 128    // max edges/row; Binomial(4096,0.01) P(>127) ~ 1e-30
#define WROW 258   // padded shorts per ws row (516 B -> bank-spread writes)
#define HPB 512    // hprime blocks (FIRST)
#define SCB 2048   // grid-stride scanbits blocks

typedef __attribute__((ext_vector_type(8))) short bf16x8;
typedef __attribute__((ext_vector_type(4))) float f32x4;

__device__ __forceinline__ unsigned short f2bf(float f) {   // RNE f32->bf16
    unsigned u = __float_as_uint(f);
    u = (u + 0x7fff + ((u >> 16) & 1)) >> 16;
    return (unsigned short)u;
}
__device__ __forceinline__ float bf2f(unsigned short s) {
    return __uint_as_float((unsigned)s << 16);
}

// ---------------------------------------------------------------------------
// K1 (fused by block range):
//  [0,HPB):    MFMA hprime (r18 verbatim): block = (head, 32-node group),
//              wave = 16 nodes x 32 outs, w transposed in LDS, B-granule =
//              one ds_read_b128. Outputs bf16 hb + node-major sd.
//  [HPB,+SCB): r10's PROVEN grid-stride scanbits (4.7 TB/s standalone):
//              tight 1-int4/thread/iter loop -> ballot bitmask (2 MB).
//              Encoding: bits[row][c*4+k] bit l <-> col = c*256 + 4*l + k.
// ---------------------------------------------------------------------------
__global__ __launch_bounds__(256) void gat_prep(
    const float* __restrict__ h, const int* __restrict__ adj,
    const float* __restrict__ w, const float* __restrict__ a_src,
    const float* __restrict__ a_dst,
    unsigned short* __restrict__ hb, float* __restrict__ sd,
    unsigned long long* __restrict__ bits)
{
    const int b = blockIdx.x, t = threadIdx.x;
    const int wv = t >> 6, lane = t & 63;

    __shared__ __align__(16) unsigned short ws[64 * WROW];  // 33 KB
    __shared__ float sdbuf[2][2][16][2];

    if (b >= HPB) {
        // ---------------- grid-stride scanbits (r10 verbatim) ----------------
        const int nvec = NN * NN / 4;                  // 4,194,304 int4
        const int step = SCB * 256;
        for (int g = (b - HPB) * 256 + t; g < nvec; g += step) {
            const int4 a = ((const int4*)adj)[g];
            const unsigned long long b0 = __ballot(a.x != 0);
            const unsigned long long b1 = __ballot(a.y != 0);
            const unsigned long long b2 = __ballot(a.z != 0);
            const unsigned long long b3 = __ballot(a.w != 0);
            const int row = g >> 10;                   // wave-uniform
            const int it  = (g >> 6) & 15;             // chunk within row
            unsigned long long mk = b0;
            mk = ((lane & 3) == 1) ? b1 : mk;
            mk = ((lane & 3) == 2) ? b2 : mk;
            mk = ((lane & 3) == 3) ? b3 : mk;
            if (lane < 4) bits[(size_t)row * 64 + it * 4 + lane] = mk;
        }
        return;
    }

    // ---------------- MFMA hprime (r18 verbatim) ----------------
    const int head = b & 3, n0 = (b >> 2) * 32;
    const int lrow = lane & 15, lk8 = lane >> 4;

#pragma unroll
    for (int i = 0; i < 16; ++i) {
        const int k  = (t >> 4) + i * 16;
        const int o4 = (t & 15) * 4;
        const float4 v = *(const float4*)(w + ((size_t)head * FIN + k) * FOUT + o4);
        ws[(o4 + 0) * WROW + k] = f2bf(v.x);
        ws[(o4 + 1) * WROW + k] = f2bf(v.y);
        ws[(o4 + 2) * WROW + k] = f2bf(v.z);
        ws[(o4 + 3) * WROW + k] = f2bf(v.w);
    }

    const float* hrow = h + (size_t)(n0 + (wv >> 1) * 16 + lrow) * FIN + lk8 * 8;
    bf16x8 a[8];
#pragma unroll
    for (int ks = 0; ks < 8; ++ks) {
        const float4 v0 = *(const float4*)(hrow + ks * 32);
        const float4 v1 = *(const float4*)(hrow + ks * 32 + 4);
        union { bf16x8 v; unsigned short s[8]; } u;
        u.s[0] = f2bf(v0.x); u.s[1] = f2bf(v0.y);
        u.s[2] = f2bf(v0.z); u.s[3] = f2bf(v0.w);
        u.s[4] = f2bf(v1.x); u.s[5] = f2bf(v1.y);
        u.s[6] = f2bf(v1.z); u.s[7] = f2bf(v1.w);
        a[ks] = u.v;
    }
    __syncthreads();

    const int obase = (wv & 1) * 32;
    f32x4 acc[2] = {{0.f,0.f,0.f,0.f},{0.f,0.f,0.f,0.f}};
#pragma unroll
    for (int ks = 0; ks < 8; ++ks) {
#pragma unroll
        for (int nt = 0; nt < 2; ++nt) {
            const bf16x8 bf = *(const bf16x8*)
                &ws[(obase + nt * 16 + lrow) * WROW + ks * 32 + lk8 * 8];
            acc[nt] = __builtin_amdgcn_mfma_f32_16x16x32_bf16(a[ks], bf, acc[nt], 0, 0, 0);
        }
    }

    const int mbase = n0 + (wv >> 1) * 16 + lk8 * 4;
#pragma unroll
    for (int nt = 0; nt < 2; ++nt)
#pragma unroll
        for (int r = 0; r < 4; ++r)
            hb[((size_t)head * NN + mbase + r) * FOUT + obase + nt * 16 + lrow] =
                f2bf(acc[nt][r]);

    float as_nt[2], ad_nt[2];
#pragma unroll
    for (int nt = 0; nt < 2; ++nt) {
        as_nt[nt] = a_src[head * FOUT + obase + nt * 16 + lrow];
        ad_nt[nt] = a_dst[head * FOUT + obase + nt * 16 + lrow];
    }
    float psr[4] = {0.f,0.f,0.f,0.f}, pdr[4] = {0.f,0.f,0.f,0.f};
#pragma unroll
    for (int nt = 0; nt < 2; ++nt)
#pragma unroll
        for (int r = 0; r < 4; ++r) {
            psr[r] = fmaf(acc[nt][r], as_nt[nt], psr[r]);
            pdr[r] = fmaf(acc[nt][r], ad_nt[nt], pdr[r]);
        }
#pragma unroll
    for (int r = 0; r < 4; ++r)
#pragma unroll
        for (int off = 1; off <= 8; off <<= 1) {
            psr[r] += __shfl_xor(psr[r], off, 64);
            pdr[r] += __shfl_xor(pdr[r], off, 64);
        }
    if (lrow == 0)
#pragma unroll
        for (int r = 0; r < 4; ++r) {
            sdbuf[wv >> 1][wv & 1][lk8 * 4 + r][0] = psr[r];
            sdbuf[wv >> 1][wv & 1][lk8 * 4 + r][1] = pdr[r];
        }
    __syncthreads();
    if ((wv & 1) == 0 && lrow == 0) {
        const int p = wv >> 1;
#pragma unroll
        for (int r = 0; r < 4; ++r) {
            const int n = lk8 * 4 + r;
            const int node = n0 + p * 16 + n;
            sd[(size_t)node * 8 + head]     = sdbuf[p][0][n][0] + sdbuf[p][1][n][0];
            sd[(size_t)node * 8 + 4 + head] = sdbuf[p][0][n][1] + sdbuf[p][1][n][1];
        }
    }
}

// ---------------------------------------------------------------------------
// K2: attn from bitmask. Block = row i (4096 blocks, 8/CU). Wave 0 decodes
// the 512 B mask into an LDS edge list; scores via one float4 pair per edge
// (all 4 heads) from sd; per-head softmax (wave = head); gather v2 (lane =
// (head, o-quad), one dwordx2 per edge, edges split p%4 across waves).
// ---------------------------------------------------------------------------
__global__ __launch_bounds__(256) void gat_attn(
    const unsigned long long* __restrict__ bits,
    const unsigned short* __restrict__ hb, const float* __restrict__ sd,
    const float* __restrict__ bias, float* __restrict__ out)
{
    const int i = blockIdx.x, t = threadIdx.x, wv = t >> 6, lane = t & 63;

    __shared__ int   idx_l[CAP];
    __shared__ float sc[NH][CAP];
    __shared__ int   cnt;
    __shared__ float inv_sum[NH];
    __shared__ float accbuf[4][64][4];

    if (wv == 0) {
        unsigned long long m = bits[(size_t)i * 64 + lane];
        const int c = __popcll(m);
        int pre = c;
#pragma unroll
        for (int off = 1; off < 64; off <<= 1) {
            const int nb = __shfl_up(pre, off, 64);
            if (lane >= off) pre += nb;
        }
        int p = pre - c;
        const int cb = (lane >> 2) * 256 + (lane & 3);
        while (m) {
            const int bpos = __ffsll((unsigned long long)m) - 1;
            if (p < CAP) idx_l[p] = cb + 4 * bpos;
            ++p;
            m &= m - 1;
        }
        if (lane == 63) cnt = pre;
    }
    __syncthreads();

    const int count = min(cnt, CAP);

    if (t < count) {
        const int j = idx_l[t];
        const float4 sv = *(const float4*)(sd + (size_t)i * 8);       // src, 4 heads
        const float4 dv = *(const float4*)(sd + (size_t)j * 8 + 4);   // dst, 4 heads
        const float s0 = sv.x + dv.x, s1 = sv.y + dv.y;
        const float s2 = sv.z + dv.z, s3 = sv.w + dv.w;
        sc[0][t] = (s0 >= 0.f) ? s0 : 0.2f * s0;
        sc[1][t] = (s1 >= 0.f) ? s1 : 0.2f * s1;
        sc[2][t] = (s2 >= 0.f) ? s2 : 0.2f * s2;
        sc[3][t] = (s3 >= 0.f) ? s3 : 0.2f * s3;
    }
    __syncthreads();

    {   // per-head softmax (wave = head)
        float m = -3.4e38f;
        for (int p = lane; p < count; p += 64) m = fmaxf(m, sc[wv][p]);
#pragma unroll
        for (int off = 32; off >= 1; off >>= 1) m = fmaxf(m, __shfl_xor(m, off, 64));
        float e = 0.f;
        for (int p = lane; p < count; p += 64) {
            const float v = __expf(sc[wv][p] - m);
            sc[wv][p] = v;
            e += v;
        }
#pragma unroll
        for (int off = 32; off >= 1; off >>= 1) e += __shfl_xor(e, off, 64);
        if (lane == 0) inv_sum[wv] = 1.f / e;
    }
    __syncthreads();

    // gather v2: lane = (hh = lane>>4, og = lane&15); wave wv takes p%4==wv.
    const int hh = lane >> 4, og = lane & 15;
    const unsigned short* hpb = hb + (size_t)hh * NN * FOUT + og * 4;
    float4 accv = make_float4(0.f, 0.f, 0.f, 0.f);
    for (int p0 = wv; p0 < count; p0 += 16) {
        int jj[4]; float ee[4]; ushort4 hv[4];
#pragma unroll
        for (int k = 0; k < 4; ++k) {
            const int pp = p0 + k * 4;
            const bool act = pp < count;
            jj[k] = act ? idx_l[pp] : 0;
            ee[k] = act ? sc[hh][pp] : 0.f;
        }
#pragma unroll
        for (int k = 0; k < 4; ++k)
            hv[k] = *(const ushort4*)(hpb + (size_t)jj[k] * FOUT);
#pragma unroll
        for (int k = 0; k < 4; ++k) {
            accv.x = fmaf(ee[k], bf2f(hv[k].x), accv.x);
            accv.y = fmaf(ee[k], bf2f(hv[k].y), accv.y);
            accv.z = fmaf(ee[k], bf2f(hv[k].z), accv.z);
            accv.w = fmaf(ee[k], bf2f(hv[k].w), accv.w);
        }
    }
    *(float4*)&accbuf[wv][lane][0] = accv;
    __syncthreads();

    if (wv == 0) {
        float4 r0 = *(const float4*)&accbuf[0][lane][0];
        const float4 r1 = *(const float4*)&accbuf[1][lane][0];
        const float4 r2 = *(const float4*)&accbuf[2][lane][0];
        const float4 r3 = *(const float4*)&accbuf[3][lane][0];
        r0.x += r1.x + r2.x + r3.x;
        r0.y += r1.y + r2.y + r3.y;
        r0.z += r1.z + r2.z + r3.z;
        r0.w += r1.w + r2.w + r3.w;
        const float is = inv_sum[hh];
        const float4 bv = *(const float4*)(bias + og * 4);
        float4 o;
        o.x = r0.x * is + bv.x;
        o.y = r0.y * is + bv.y;
        o.z = r0.z * is + bv.z;
        o.w = r0.w * is + bv.w;
        *(float4*)(out + (size_t)i * (NH * FOUT) + hh * FOUT + og * 4) = o;
    }
}

extern "C" void kernel_launch(void* const* d_in, const int* in_sizes, int n_in,
                              void* d_out, int out_size, void* d_ws, size_t ws_size,
                              hipStream_t stream) {
    const float* h     = (const float*)d_in[0];
    const int*   adj   = (const int*)d_in[1];
    const float* w     = (const float*)d_in[2];
    const float* a_src = (const float*)d_in[3];
    const float* a_dst = (const float*)d_in[4];
    const float* bias  = (const float*)d_in[5];
    float* out = (float*)d_out;

    unsigned short* hb = (unsigned short*)d_ws;                 // 2 MB bf16 h'
    float* sd          = (float*)(hb + (size_t)NH * NN * FOUT); // NN*8 floats
    unsigned long long* bits = (unsigned long long*)(sd + (size_t)NN * 8); // 2 MB

    gat_prep<<<HPB + SCB, 256, 0, stream>>>(h, adj, w, a_src, a_dst, hb, sd, bits);
    gat_attn<<<NN, 256, 0, stream>>>(bits, hb, sd, bias, out);
}

// Round 26
// 34.017 us; speedup vs baseline: 1.1763x; 1.0372x over previous
//
#include <hip/hip_runtime.h>

#define NN 4096
#define FIN 256
#define FOUT 64
#define NH 4
#define CAP 128    // max edges/row; Binomial(4096,0.01) P(>127) ~ 1e-30
#define WROW 258   // padded shorts per ws row (516 B -> bank-spread writes)

typedef __attribute__((ext_vector_type(8))) short bf16x8;
typedef __attribute__((ext_vector_type(4))) float f32x4;

__device__ __forceinline__ unsigned short f2bf(float f) {   // RNE f32->bf16
    unsigned u = __float_as_uint(f);
    u = (u + 0x7fff + ((u >> 16) & 1)) >> 16;
    return (unsigned short)u;
}
__device__ __forceinline__ float bf2f(unsigned short s) {
    return __uint_as_float((unsigned)s << 16);
}
__device__ __forceinline__ int mbcnt64(unsigned long long m) {
    return __builtin_amdgcn_mbcnt_hi((unsigned)(m >> 32),
           __builtin_amdgcn_mbcnt_lo((unsigned)m, 0));
}

// ---------------------------------------------------------------------------
// K1: MFMA hprime (r18 verbatim). 512 blocks = (head, 32-node group);
// wave = 16 nodes x 32 outs; w staged transposed in LDS; B-granule = one
// ds_read_b128. Outputs bf16 hb [head][node][o] + node-major sd.
// ---------------------------------------------------------------------------
__global__ __launch_bounds__(256) void gat_hprime(
    const float* __restrict__ h, const float* __restrict__ w,
    const float* __restrict__ a_src, const float* __restrict__ a_dst,
    unsigned short* __restrict__ hb, float* __restrict__ sd)
{
    const int b = blockIdx.x, t = threadIdx.x;
    const int head = b & 3, n0 = (b >> 2) * 32;
    const int wv = t >> 6, lane = t & 63;
    const int lrow = lane & 15, lk8 = lane >> 4;

    __shared__ __align__(16) unsigned short ws[64 * WROW];  // 33 KB
    __shared__ float sdbuf[2][2][16][2];

#pragma unroll
    for (int i = 0; i < 16; ++i) {
        const int k  = (t >> 4) + i * 16;
        const int o4 = (t & 15) * 4;
        const float4 v = *(const float4*)(w + ((size_t)head * FIN + k) * FOUT + o4);
        ws[(o4 + 0) * WROW + k] = f2bf(v.x);
        ws[(o4 + 1) * WROW + k] = f2bf(v.y);
        ws[(o4 + 2) * WROW + k] = f2bf(v.z);
        ws[(o4 + 3) * WROW + k] = f2bf(v.w);
    }

    const float* hrow = h + (size_t)(n0 + (wv >> 1) * 16 + lrow) * FIN + lk8 * 8;
    bf16x8 a[8];
#pragma unroll
    for (int ks = 0; ks < 8; ++ks) {
        const float4 v0 = *(const float4*)(hrow + ks * 32);
        const float4 v1 = *(const float4*)(hrow + ks * 32 + 4);
        union { bf16x8 v; unsigned short s[8]; } u;
        u.s[0] = f2bf(v0.x); u.s[1] = f2bf(v0.y);
        u.s[2] = f2bf(v0.z); u.s[3] = f2bf(v0.w);
        u.s[4] = f2bf(v1.x); u.s[5] = f2bf(v1.y);
        u.s[6] = f2bf(v1.z); u.s[7] = f2bf(v1.w);
        a[ks] = u.v;
    }
    __syncthreads();

    const int obase = (wv & 1) * 32;
    f32x4 acc[2] = {{0.f,0.f,0.f,0.f},{0.f,0.f,0.f,0.f}};
#pragma unroll
    for (int ks = 0; ks < 8; ++ks) {
#pragma unroll
        for (int nt = 0; nt < 2; ++nt) {
            const bf16x8 bf = *(const bf16x8*)
                &ws[(obase + nt * 16 + lrow) * WROW + ks * 32 + lk8 * 8];
            acc[nt] = __builtin_amdgcn_mfma_f32_16x16x32_bf16(a[ks], bf, acc[nt], 0, 0, 0);
        }
    }

    const int mbase = n0 + (wv >> 1) * 16 + lk8 * 4;
#pragma unroll
    for (int nt = 0; nt < 2; ++nt)
#pragma unroll
        for (int r = 0; r < 4; ++r)
            hb[((size_t)head * NN + mbase + r) * FOUT + obase + nt * 16 + lrow] =
                f2bf(acc[nt][r]);

    float as_nt[2], ad_nt[2];
#pragma unroll
    for (int nt = 0; nt < 2; ++nt) {
        as_nt[nt] = a_src[head * FOUT + obase + nt * 16 + lrow];
        ad_nt[nt] = a_dst[head * FOUT + obase + nt * 16 + lrow];
    }
    float psr[4] = {0.f,0.f,0.f,0.f}, pdr[4] = {0.f,0.f,0.f,0.f};
#pragma unroll
    for (int nt = 0; nt < 2; ++nt)
#pragma unroll
        for (int r = 0; r < 4; ++r) {
            psr[r] = fmaf(acc[nt][r], as_nt[nt], psr[r]);
            pdr[r] = fmaf(acc[nt][r], ad_nt[nt], pdr[r]);
        }
#pragma unroll
    for (int r = 0; r < 4; ++r)
#pragma unroll
        for (int off = 1; off <= 8; off <<= 1) {
            psr[r] += __shfl_xor(psr[r], off, 64);
            pdr[r] += __shfl_xor(pdr[r], off, 64);
        }
    if (lrow == 0)
#pragma unroll
        for (int r = 0; r < 4; ++r) {
            sdbuf[wv >> 1][wv & 1][lk8 * 4 + r][0] = psr[r];
            sdbuf[wv >> 1][wv & 1][lk8 * 4 + r][1] = pdr[r];
        }
    __syncthreads();
    if ((wv & 1) == 0 && lrow == 0) {
        const int p = wv >> 1;
#pragma unroll
        for (int r = 0; r < 4; ++r) {
            const int n = lk8 * 4 + r;
            const int node = n0 + p * 16 + n;
            sd[(size_t)node * 8 + head]     = sdbuf[p][0][n][0] + sdbuf[p][1][n][0];
            sd[(size_t)node * 8 + 4 + head] = sdbuf[p][0][n][1] + sdbuf[p][1][n][1];
        }
    }
}

// ---------------------------------------------------------------------------
// K2: fused scan+attn (r21 structure, 4096 blocks) with the score+softmax
// phase done IN-REGISTER per wave (wave = head; lane owns edges p=lane and
// p=lane+64; scalar dst-logit loads; shfl max/sum; single P-write to LDS).
// 4 barriers instead of 6, ~150 fewer wave-instructions per row.
// ---------------------------------------------------------------------------
__global__ __launch_bounds__(256) void gat_attn(
    const int* __restrict__ adj, const unsigned short* __restrict__ hb,
    const float* __restrict__ sd, const float* __restrict__ bias,
    float* __restrict__ out)
{
    const int i = blockIdx.x, t = threadIdx.x, wv = t >> 6, lane = t & 63;

    __shared__ int   idx_l[CAP];
    __shared__ float sc[NH][CAP];
    __shared__ int   ccnt[16];
    __shared__ float inv_sum[NH];
    __shared__ float accbuf[4][64][4];   // per-wave gather partials

    // Phase A: issue my 4 int4 loads of the row back-to-back
    const int4* arow = (const int4*)(adj + (size_t)i * NN);
    int4 a[4];
#pragma unroll
    for (int it = 0; it < 4; ++it) a[it] = arow[wv * 256 + it * 64 + lane];

    // Phase B: ballots -> within-chunk offset + per-chunk count
    int myoff[4];
#pragma unroll
    for (int it = 0; it < 4; ++it) {
        const unsigned long long b0 = __ballot(a[it].x != 0);
        const unsigned long long b1 = __ballot(a[it].y != 0);
        const unsigned long long b2 = __ballot(a[it].z != 0);
        const unsigned long long b3 = __ballot(a[it].w != 0);
        myoff[it] = mbcnt64(b0) + mbcnt64(b1) + mbcnt64(b2) + mbcnt64(b3);
        if (lane == 0)
            ccnt[wv * 4 + it] = __popcll(b0) + __popcll(b1) +
                                __popcll(b2) + __popcll(b3);
    }
    __syncthreads();

    // chunk-prefix (16 chunks) -> deterministic layout
    int cb[4];
    int s = 0;
#pragma unroll
    for (int k = 0; k < 16; ++k) {
        if ((k >> 2) == wv) cb[k & 3] = s;
        s += ccnt[k];
    }
    const int count = min(s, CAP);

    // Phase C: scatter edge columns into LDS
#pragma unroll
    for (int it = 0; it < 4; ++it) {
        int p = cb[it] + myoff[it];
        const int col0 = (wv * 256 + it * 64 + lane) * 4;
        if (a[it].x) { if (p < CAP) idx_l[p] = col0;     ++p; }
        if (a[it].y) { if (p < CAP) idx_l[p] = col0 + 1; ++p; }
        if (a[it].z) { if (p < CAP) idx_l[p] = col0 + 2; ++p; }
        if (a[it].w) { if (p < CAP) idx_l[p] = col0 + 3; ++p; }
    }
    __syncthreads();

    // Phase D: in-register scores + softmax; wave = head wv.
    // Lane owns edges p=lane and p=lane+64 (count <= 128).
    {
        const float sv_h = sd[(size_t)i * 8 + wv];         // wave-uniform
        const bool actA = lane < count, actB = lane + 64 < count;
        const int jA = actA ? idx_l[lane] : 0;
        const int jB = actB ? idx_l[lane + 64] : 0;
        float vA = sv_h + sd[(size_t)jA * 8 + 4 + wv];
        float vB = sv_h + sd[(size_t)jB * 8 + 4 + wv];
        vA = (vA >= 0.f) ? vA : 0.2f * vA;                 // leaky_relu(0.2)
        vB = (vB >= 0.f) ? vB : 0.2f * vB;
        const float sA = actA ? vA : -3.4e38f;
        const float sB = actB ? vB : -3.4e38f;

        float m = fmaxf(sA, sB);
#pragma unroll
        for (int off = 32; off >= 1; off >>= 1)
            m = fmaxf(m, __shfl_xor(m, off, 64));
        const float eA = actA ? __expf(sA - m) : 0.f;
        const float eB = actB ? __expf(sB - m) : 0.f;
        float e = eA + eB;
#pragma unroll
        for (int off = 32; off >= 1; off >>= 1)
            e += __shfl_xor(e, off, 64);
        if (lane == 0) inv_sum[wv] = 1.f / e;
        sc[wv][lane]      = eA;                            // P weights
        sc[wv][lane + 64] = eB;
    }
    __syncthreads();

    // Phase E: gather v2. lane = (hh = lane>>4, og = lane&15); wave wv takes
    // p%4==wv; one dwordx2 per edge = 4 consecutive outs of head hh.
    const int hh = lane >> 4, og = lane & 15;
    const unsigned short* hpb = hb + (size_t)hh * NN * FOUT + og * 4;
    float4 accv = make_float4(0.f, 0.f, 0.f, 0.f);
    for (int p0 = wv; p0 < count; p0 += 16) {
        int jj[4]; float ee[4]; ushort4 hv[4];
#pragma unroll
        for (int k = 0; k < 4; ++k) {
            const int pp = p0 + k * 4;
            const bool act = pp < count;
            jj[k] = act ? idx_l[pp] : 0;
            ee[k] = act ? sc[hh][pp] : 0.f;
        }
#pragma unroll
        for (int k = 0; k < 4; ++k)
            hv[k] = *(const ushort4*)(hpb + (size_t)jj[k] * FOUT);
#pragma unroll
        for (int k = 0; k < 4; ++k) {
            accv.x = fmaf(ee[k], bf2f(hv[k].x), accv.x);
            accv.y = fmaf(ee[k], bf2f(hv[k].y), accv.y);
            accv.z = fmaf(ee[k], bf2f(hv[k].z), accv.z);
            accv.w = fmaf(ee[k], bf2f(hv[k].w), accv.w);
        }
    }
    *(float4*)&accbuf[wv][lane][0] = accv;
    __syncthreads();

    // Phase F: combine wave-partials; wave 0 writes coalesced float4 outputs
    if (wv == 0) {
        float4 r0 = *(const float4*)&accbuf[0][lane][0];
        const float4 r1 = *(const float4*)&accbuf[1][lane][0];
        const float4 r2 = *(const float4*)&accbuf[2][lane][0];
        const float4 r3 = *(const float4*)&accbuf[3][lane][0];
        r0.x += r1.x + r2.x + r3.x;
        r0.y += r1.y + r2.y + r3.y;
        r0.z += r1.z + r2.z + r3.z;
        r0.w += r1.w + r2.w + r3.w;
        const float is = inv_sum[hh];
        const float4 bv = *(const float4*)(bias + og * 4);
        float4 o;
        o.x = r0.x * is + bv.x;
        o.y = r0.y * is + bv.y;
        o.z = r0.z * is + bv.z;
        o.w = r0.w * is + bv.w;
        *(float4*)(out + (size_t)i * (NH * FOUT) + hh * FOUT + og * 4) = o;
    }
}

extern "C" void kernel_launch(void* const* d_in, const int* in_sizes, int n_in,
                              void* d_out, int out_size, void* d_ws, size_t ws_size,
                              hipStream_t stream) {
    const float* h     = (const float*)d_in[0];
    const int*   adj   = (const int*)d_in[1];
    const float* w     = (const float*)d_in[2];
    const float* a_src = (const float*)d_in[3];
    const float* a_dst = (const float*)d_in[4];
    const float* bias  = (const float*)d_in[5];
    float* out = (float*)d_out;

    unsigned short* hb = (unsigned short*)d_ws;                 // 2 MB bf16 h'
    float* sd          = (float*)(hb + (size_t)NH * NN * FOUT); // NN*8 floats

    gat_hprime<<<512, 256, 0, stream>>>(h, w, a_src, a_dst, hb, sd);
    gat_attn<<<NN, 256, 0, stream>>>(adj, hb, sd, bias, out);
}